// Round 1
// baseline (247.393 us; speedup 1.0000x reference)
//
#include <hip/hip_runtime.h>
#include <stdint.h>

typedef __bf16 bf16x8 __attribute__((ext_vector_type(8)));
typedef float f32x16 __attribute__((ext_vector_type(16)));

#define H 128
#define NBINF 11
#define NCHUNK 17   // 8 local + 8 global + 1 binary (11 padded to 16)
#define PTOT 640000

// weight packs live in static device memory (no reliance on ws_size)
__device__ __align__(16) unsigned short g_wpack[NCHUNK * 4 * 64 * 8]; // 34816 bf16
__device__ __align__(16) unsigned short g_wsp[8 * 64 * 8];            // 4096 bf16
__device__ int g_flag;                                                // idx dword stride: 1 (int32) or 2 (int64)

__device__ __forceinline__ uint32_t f2bf_u(float f) {
  uint32_t u = __float_as_uint(f);
  return (u + 0x7FFFu + ((u >> 16) & 1u)) >> 16; // RNE, no NaN inputs here
}
__device__ __forceinline__ uint32_t pk_bf(float lo, float hi) {
  return (f2bf_u(lo) & 0xFFFFu) | (f2bf_u(hi) << 16);
}

// Detect whether sparse_idx is int32 (stride 1) or int64 (stride 2).
// For int64 little-endian non-negative small values, every odd dword is 0.
__global__ void k_flag(const int* __restrict__ sidx) {
  int t = threadIdx.x;                 // one wave (64 threads)
  int v = sidx[2 * t + 1];
  unsigned long long any = __ballot(v != 0);
  if (t == 0) g_flag = (any == 0ull) ? 2 : 1;
}

// Pack W_cat (272x128) and W_score (128x5 padded to 128x32) into
// MFMA B-fragment-native bf16 layout: [chunk][ntile][lane][8].
__global__ void k_pack(const float* __restrict__ Wl, const float* __restrict__ Wg,
                       const float* __restrict__ Wb, const float* __restrict__ Wsc) {
  int tid = blockIdx.x * 256 + threadIdx.x;
  if (tid < NCHUNK * 4 * 64 * 8) {
    int j = tid & 7, l = (tid >> 3) & 63, nt = (tid >> 9) & 3, c = tid >> 11;
    int k = c * 16 + ((l >> 5) << 3) + j;   // K index in [0,272)
    int n = nt * 32 + (l & 31);             // N index in [0,128)
    float v = 0.f;
    if (k < 128)       v = Wl[k * H + n];
    else if (k < 256)  v = Wg[(k - 128) * H + n];
    else { int kk = k - 256; v = (kk < NBINF) ? Wb[kk * H + n] : 0.f; }
    g_wpack[tid] = (unsigned short)f2bf_u(v);
  }
  if (tid < 8 * 64 * 8) {
    int j = tid & 7, l = (tid >> 3) & 63, cs = tid >> 9; // cs = nt*2 + c2
    int h = (cs >> 1) * 32 + (cs & 1) * 16 + ((l >> 5) << 3) + j; // [0,128)
    int s = l & 31;                                               // score col
    float v = (s < 5) ? Wsc[h * 5 + s] : 0.f;
    g_wsp[tid] = (unsigned short)f2bf_u(v);
  }
}

__launch_bounds__(256, 3)
__global__ void k_main(const float* __restrict__ lp, const float* __restrict__ gp,
                       const float* __restrict__ bin, const int* __restrict__ sidx,
                       const float* __restrict__ bg, const float* __restrict__ bsc,
                       float* __restrict__ out) {
  __shared__ __align__(16) float pf[4][32 * 36]; // per-wave transpose buffer
  const int wid = threadIdx.x >> 6;
  const int l   = threadIdx.x & 63;
  const int lr  = l & 31;   // A row within tile / B col within ntile
  const int lh  = l >> 5;   // k-half selector
  const int p0  = blockIdx.x * 128 + wid * 32;
  const int prow = p0 + lr;

  // ---- gather binary feats for this row ----
  const int stride = g_flag;
  int bidx = sidx[(prow * 3 + 0) * stride];
  int iidx = sidx[(prow * 3 + 1) * stride];
  int jidx = sidx[(prow * 3 + 2) * stride];
  int base = ((bidx * 100 + iidx) * 100 + jidx) * NBINF;

  float binf[8];
#pragma unroll
  for (int j = 0; j < 8; ++j) {
    int e = lh * 8 + j;
    binf[j] = (e < NBINF) ? bin[base + e] : 0.f;
  }

  const float* Al = lp + (size_t)prow * H + lh * 8;
  const float* Ag = gp + (size_t)prow * H + lh * 8;

  // ---- main GEMM: acc[nt] = A(32x272) @ Wcat(272x128), fp32 accum ----
  f32x16 acc[4] = {};
#pragma unroll
  for (int c = 0; c < NCHUNK; ++c) {
    float av[8];
    if (c < 8) {
      const float4* s = (const float4*)(Al + c * 16);
      float4 x0 = s[0], x1 = s[1];
      av[0] = x0.x; av[1] = x0.y; av[2] = x0.z; av[3] = x0.w;
      av[4] = x1.x; av[5] = x1.y; av[6] = x1.z; av[7] = x1.w;
    } else if (c < 16) {
      const float4* s = (const float4*)(Ag + (c - 8) * 16);
      float4 x0 = s[0], x1 = s[1];
      av[0] = x0.x; av[1] = x0.y; av[2] = x0.z; av[3] = x0.w;
      av[4] = x1.x; av[5] = x1.y; av[6] = x1.z; av[7] = x1.w;
    } else {
#pragma unroll
      for (int j = 0; j < 8; ++j) av[j] = binf[j];
    }
    union { uint32_t w[4]; bf16x8 v; } fa;
    fa.w[0] = pk_bf(av[0], av[1]);
    fa.w[1] = pk_bf(av[2], av[3]);
    fa.w[2] = pk_bf(av[4], av[5]);
    fa.w[3] = pk_bf(av[6], av[7]);
#pragma unroll
    for (int nt = 0; nt < 4; ++nt) {
      bf16x8 wb = *(const bf16x8*)(g_wpack + ((size_t)(c * 4 + nt) * 64 + l) * 8);
      acc[nt] = __builtin_amdgcn_mfma_f32_32x32x16_bf16(fa.v, wb, acc[nt], 0, 0, 0);
    }
  }

  // ---- epilogue: bias + relu, LDS transpose, score MFMA ----
  f32x16 sacc = {};
  float* buf = pf[wid];
#pragma unroll
  for (int nt = 0; nt < 4; ++nt) {
    float bgv = bg[nt * 32 + lr];
#pragma unroll
    for (int rg = 0; rg < 16; ++rg) {
      int r = (rg & 3) + ((rg >> 2) << 3) + (lh << 2);
      buf[r * 36 + lr] = fmaxf(acc[nt][rg] + bgv, 0.f); // pf[r][h'] h'=lr
    }
    asm volatile("s_waitcnt lgkmcnt(0)" ::: "memory"); // cross-lane RAW in wave
#pragma unroll
    for (int c2 = 0; c2 < 2; ++c2) {
      const float* src = buf + lr * 36 + c2 * 16 + lh * 8; // pf[row=lr][k]
      float4 x0 = *(const float4*)src;
      float4 x1 = *(const float4*)(src + 4);
      union { uint32_t w[4]; bf16x8 v; } fa;
      fa.w[0] = pk_bf(x0.x, x0.y);
      fa.w[1] = pk_bf(x0.z, x0.w);
      fa.w[2] = pk_bf(x1.x, x1.y);
      fa.w[3] = pk_bf(x1.z, x1.w);
      bf16x8 wb = *(const bf16x8*)(g_wsp + ((size_t)((nt * 2 + c2) * 64 + l)) * 8);
      sacc = __builtin_amdgcn_mfma_f32_32x32x16_bf16(fa.v, wb, sacc, 0, 0, 0);
    }
    asm volatile("s_waitcnt lgkmcnt(0)" ::: "memory"); // WAR before next nt
  }

  // ---- store: lane holds score[r][s=lr] for 16 r values ----
  if (lr < 5) {
    float bs = bsc[lr];
    float* op = out + (size_t)p0 * 5 + lr;
#pragma unroll
    for (int rg = 0; rg < 16; ++rg) {
      int r = (rg & 3) + ((rg >> 2) << 3) + (lh << 2);
      op[r * 5] = sacc[rg] + bs;
    }
  }
}

extern "C" void kernel_launch(void* const* d_in, const int* in_sizes, int n_in,
                              void* d_out, int out_size, void* d_ws, size_t ws_size,
                              hipStream_t stream) {
  const float* lp  = (const float*)d_in[0];
  const float* gp  = (const float*)d_in[1];
  const float* bin = (const float*)d_in[2];
  const int*   si  = (const int*)d_in[3];
  const float* Wl  = (const float*)d_in[4];
  const float* Wg  = (const float*)d_in[5];
  const float* bg  = (const float*)d_in[6];
  const float* Wb  = (const float*)d_in[7];
  const float* Wsc = (const float*)d_in[8];
  const float* bsc = (const float*)d_in[9];
  float* out = (float*)d_out;

  hipLaunchKernelGGL(k_flag, dim3(1), dim3(64), 0, stream, si);
  hipLaunchKernelGGL(k_pack, dim3(136), dim3(256), 0, stream, Wl, Wg, Wb, Wsc);
  hipLaunchKernelGGL(k_main, dim3(PTOT / 128), dim3(256), 0, stream,
                     lp, gp, bin, si, bg, bsc, out);
}

// Round 2
// 170.391 us; speedup vs baseline: 1.4519x; 1.4519x over previous
//
#include <hip/hip_runtime.h>
#include <stdint.h>

typedef __bf16 bf16x8 __attribute__((ext_vector_type(8)));
typedef float f32x16 __attribute__((ext_vector_type(16)));

#define H 128
#define NBINF 11
#define NCHUNK 17   // 8 local + 8 global + 1 binary (11 padded to 16)
#define PTOT 640000
#define ROWS 64     // rows per block
#define ASTRIDE 560 // bytes per LDS A row: 280 bf16 (272 + 8 pad)
#define FSTRIDE 272 // bytes per LDS feat row: 136 bf16 (128 + 8 pad)

__device__ __align__(16) unsigned short g_wpack[NCHUNK * 4 * 64 * 8]; // [c][nt][lane][8]
__device__ __align__(16) unsigned short g_wsp[8 * 64 * 8];            // [cs][lane][8]
__device__ int g_flag; // idx dword stride: 1 (int32) or 2 (int64)

__device__ __forceinline__ uint32_t f2bf_u(float f) {
  uint32_t u = __float_as_uint(f);
  return (u + 0x7FFFu + ((u >> 16) & 1u)) >> 16; // RNE
}
__device__ __forceinline__ uint32_t pk_bf(float lo, float hi) {
  return (f2bf_u(lo) & 0xFFFFu) | (f2bf_u(hi) << 16);
}

__global__ void k_flag(const int* __restrict__ sidx) {
  int t = threadIdx.x;
  int v = sidx[2 * t + 1];
  unsigned long long any = __ballot(v != 0);
  if (t == 0) g_flag = (any == 0ull) ? 2 : 1;
}

__global__ void k_pack(const float* __restrict__ Wl, const float* __restrict__ Wg,
                       const float* __restrict__ Wb, const float* __restrict__ Wsc) {
  int tid = blockIdx.x * 256 + threadIdx.x;
  if (tid < NCHUNK * 4 * 64 * 8) {
    int j = tid & 7, l = (tid >> 3) & 63, nt = (tid >> 9) & 3, c = tid >> 11;
    int k = c * 16 + ((l >> 5) << 3) + j;
    int n = nt * 32 + (l & 31);
    float v = 0.f;
    if (k < 128)       v = Wl[k * H + n];
    else if (k < 256)  v = Wg[(k - 128) * H + n];
    else { int kk = k - 256; v = (kk < NBINF) ? Wb[kk * H + n] : 0.f; }
    g_wpack[tid] = (unsigned short)f2bf_u(v);
  }
  if (tid < 8 * 64 * 8) {
    int j = tid & 7, l = (tid >> 3) & 63, cs = tid >> 9;
    int h = (cs >> 1) * 32 + (cs & 1) * 16 + ((l >> 5) << 3) + j;
    int s = l & 31;
    float v = (s < 5) ? Wsc[h * 5 + s] : 0.f;
    g_wsp[tid] = (unsigned short)f2bf_u(v);
  }
}

__launch_bounds__(256, 3)
__global__ void k_main(const float* __restrict__ lp, const float* __restrict__ gp,
                       const float* __restrict__ bin, const int* __restrict__ sidx,
                       const float* __restrict__ bg, const float* __restrict__ bsc,
                       float* __restrict__ out) {
  __shared__ __align__(16) char sm[ROWS * ASTRIDE]; // 35840 B; feat buf reuses it
  const int t   = threadIdx.x;
  const int wid = t >> 6;
  const int l   = t & 63;
  const int lr  = l & 31;
  const int lh  = l >> 5;
  const int p0  = blockIdx.x * ROWS;

  // ---- weight slice for this wave: 17 chunks x 16B/lane (68 VGPR) ----
  bf16x8 wreg[NCHUNK];
#pragma unroll
  for (int c = 0; c < NCHUNK; ++c)
    wreg[c] = *(const bf16x8*)(g_wpack + ((size_t)(c * 4 + wid) * 64 + l) * 8);

  // ---- stage A (local||global) into LDS as bf16: 8 units of 8 floats ----
#pragma unroll
  for (int i = 0; i < 8; ++i) {
    int u = t + i * 256;               // 0..2047
    int row = u >> 5, slot = u & 31;   // slot = c*2+lh, k0 = slot*8
    const float* src = (slot < 16)
        ? lp + (size_t)(p0 + row) * H + slot * 8
        : gp + (size_t)(p0 + row) * H + (slot - 16) * 8;
    float4 x0 = ((const float4*)src)[0];
    float4 x1 = ((const float4*)src)[1];
    uint4 pk = make_uint4(pk_bf(x0.x, x0.y), pk_bf(x0.z, x0.w),
                          pk_bf(x1.x, x1.y), pk_bf(x1.z, x1.w));
    *(uint4*)(sm + row * ASTRIDE + slot * 16) = pk;
  }
  // ---- stage binary gather (chunk 16) ----
  if (t < 2 * ROWS) {
    int row = t >> 1, bh = t & 1;
    int prow = p0 + row;
    const int stride = g_flag;
    int bi = sidx[(prow * 3 + 0) * stride];
    int ii = sidx[(prow * 3 + 1) * stride];
    int jj = sidx[(prow * 3 + 2) * stride];
    int base = ((bi * 100 + ii) * 100 + jj) * NBINF;
    float v[8];
#pragma unroll
    for (int j = 0; j < 8; ++j) {
      int e = bh * 8 + j;
      v[j] = (e < NBINF) ? bin[base + e] : 0.f;
    }
    uint4 pk = make_uint4(pk_bf(v[0], v[1]), pk_bf(v[2], v[3]),
                          pk_bf(v[4], v[5]), pk_bf(v[6], v[7]));
    *(uint4*)(sm + row * ASTRIDE + 512 + bh * 16) = pk;
  }
  __syncthreads();

  // ---- main GEMM: 2 row-tiles x 17 chunks, weights in regs ----
  f32x16 acc[2] = {};
#pragma unroll
  for (int c = 0; c < NCHUNK; ++c) {
#pragma unroll
    for (int rt = 0; rt < 2; ++rt) {
      bf16x8 a = *(const bf16x8*)(sm + (rt * 32 + lr) * ASTRIDE + c * 32 + lh * 16);
      acc[rt] = __builtin_amdgcn_mfma_f32_32x32x16_bf16(a, wreg[c], acc[rt], 0, 0, 0);
    }
  }
  __syncthreads(); // all reads of A done before overwriting with feats

  // ---- bias + relu -> feat LDS (bf16, row-major, stride 136) ----
  {
    float bgv = bg[wid * 32 + lr];
#pragma unroll
    for (int rt = 0; rt < 2; ++rt) {
#pragma unroll
      for (int r = 0; r < 16; ++r) {
        int row_t = (r & 3) + ((r >> 2) << 3) + (lh << 2);
        float v = fmaxf(acc[rt][r] + bgv, 0.f);
        *(unsigned short*)(sm + (size_t)(rt * 32 + row_t) * FSTRIDE +
                           (size_t)(wid * 32 + lr) * 2) = (unsigned short)f2bf_u(v);
      }
    }
  }
  __syncthreads();

  // ---- score GEMM on waves 0,1: tile = wid, K=128 (8 chunks) ----
  if (wid < 2) {
    bf16x8 ws[8];
#pragma unroll
    for (int cs = 0; cs < 8; ++cs)
      ws[cs] = *(const bf16x8*)(g_wsp + ((size_t)cs * 64 + l) * 8);
    f32x16 sacc = {};
#pragma unroll
    for (int cs = 0; cs < 8; ++cs) {
      bf16x8 a = *(const bf16x8*)(sm + (size_t)(wid * 32 + lr) * FSTRIDE +
                                  cs * 32 + lh * 16);
      sacc = __builtin_amdgcn_mfma_f32_32x32x16_bf16(a, ws[cs], sacc, 0, 0, 0);
    }
    if (lr < 5) {
      float bs = bsc[lr];
      float* op = out + (size_t)(p0 + wid * 32) * 5 + lr;
#pragma unroll
      for (int r = 0; r < 16; ++r) {
        int row_t = (r & 3) + ((r >> 2) << 3) + (lh << 2);
        op[row_t * 5] = sacc[r] + bs;
      }
    }
  }
}

extern "C" void kernel_launch(void* const* d_in, const int* in_sizes, int n_in,
                              void* d_out, int out_size, void* d_ws, size_t ws_size,
                              hipStream_t stream) {
  const float* lp  = (const float*)d_in[0];
  const float* gp  = (const float*)d_in[1];
  const float* bin = (const float*)d_in[2];
  const int*   si  = (const int*)d_in[3];
  const float* Wl  = (const float*)d_in[4];
  const float* Wg  = (const float*)d_in[5];
  const float* bg  = (const float*)d_in[6];
  const float* Wb  = (const float*)d_in[7];
  const float* Wsc = (const float*)d_in[8];
  const float* bsc = (const float*)d_in[9];
  float* out = (float*)d_out;

  hipLaunchKernelGGL(k_flag, dim3(1), dim3(64), 0, stream, si);
  hipLaunchKernelGGL(k_pack, dim3(136), dim3(256), 0, stream, Wl, Wg, Wb, Wsc);
  hipLaunchKernelGGL(k_main, dim3(PTOT / ROWS), dim3(256), 0, stream,
                     lp, gp, bin, si, bg, bsc, out);
}

// Round 3
// 147.323 us; speedup vs baseline: 1.6793x; 1.1566x over previous
//
#include <hip/hip_runtime.h>
#include <stdint.h>

typedef __bf16 bf16x8 __attribute__((ext_vector_type(8)));
typedef float f32x16 __attribute__((ext_vector_type(16)));

#define H 128
#define NBINF 11
#define NCHUNK 17     // 8 local + 8 global + 1 binary(11+5 pad)
#define PTOT 640000
#define ROWS 64
#define NT (PTOT / ROWS)   // 10000 tiles
#define GRID 512           // 2 blocks/CU, persistent
#define ASTRIDE 560        // bytes per LDS A row: 280 bf16 (272 + 8 pad)
#define ABUF (ROWS * ASTRIDE) // 35840 B per buffer
#define FSTRIDE 272        // bytes per feat row: 136 bf16

__device__ __align__(16) unsigned short g_wpack[NCHUNK * 4 * 64 * 8]; // [c][nt][lane][8] B-frags
__device__ __align__(16) unsigned short g_wsp[8 * 64 * 8];            // [cs][lane][8] WscT A-frags
__device__ int g_flag; // sparse_idx dword stride: 1 (int32) or 2 (int64)

__device__ __forceinline__ unsigned short f2bf(float f) {
  return (unsigned short)__builtin_bit_cast(unsigned short, (__bf16)f);
}

__global__ void k_flag(const int* __restrict__ sidx) {
  int t = threadIdx.x;
  int v = sidx[2 * t + 1];
  unsigned long long any = __ballot(v != 0);
  if (t == 0) g_flag = (any == 0ull) ? 2 : 1;
}

__global__ void k_pack(const float* __restrict__ Wl, const float* __restrict__ Wg,
                       const float* __restrict__ Wb, const float* __restrict__ Wsc) {
  int tid = blockIdx.x * 256 + threadIdx.x;
  if (tid < NCHUNK * 4 * 64 * 8) {
    int j = tid & 7, l = (tid >> 3) & 63, nt = (tid >> 9) & 3, c = tid >> 11;
    int k = c * 16 + ((l >> 5) << 3) + j;   // K in [0,272)
    int n = nt * 32 + (l & 31);             // N in [0,128)
    float v = 0.f;
    if (k < 128)       v = Wl[k * H + n];
    else if (k < 256)  v = Wg[(k - 128) * H + n];
    else { int kk = k - 256; v = (kk < NBINF) ? Wb[kk * H + n] : 0.f; }
    g_wpack[tid] = f2bf(v);
  }
  if (tid < 8 * 64 * 8) {
    // transposed score weights as MFMA A-operand: A[s][k], s=lane&31, k=cs*16+(l>>5)*8+j
    int j = tid & 7, l = (tid >> 3) & 63, cs = tid >> 9;
    int s = l & 31;
    int k = cs * 16 + ((l >> 5) << 3) + j;  // [0,128)
    float v = (s < 5) ? Wsc[k * 5 + s] : 0.f;
    g_wsp[tid] = f2bf(v);
  }
}

__device__ __forceinline__ void bar_lgkm() {
  asm volatile("s_waitcnt lgkmcnt(0)" ::: "memory");
  __builtin_amdgcn_s_barrier();
}

__launch_bounds__(256, 2)
__global__ void k_main(const float* __restrict__ lp, const float* __restrict__ gp,
                       const float* __restrict__ bin, const int* __restrict__ sidx,
                       const float* __restrict__ bg, const float* __restrict__ bsc,
                       float* __restrict__ out) {
  __shared__ __align__(16) char sm[2 * ABUF]; // 71680 B -> 2 blocks/CU
  const int t   = threadIdx.x;
  const int wid = t >> 6;
  const int l   = t & 63;
  const int lr  = l & 31;
  const int lh  = l >> 5;
  const int sflag = g_flag;

  // main-GEMM weight slice for this wave (B-frags, 68 VGPR)
  bf16x8 wreg[NCHUNK];
#pragma unroll
  for (int c = 0; c < NCHUNK; ++c)
    wreg[c] = *(const bf16x8*)(g_wpack + ((size_t)(c * 4 + wid) * 64 + l) * 8);
  // score weights (WscT A-frags, used by waves 0,1)
  bf16x8 ws[8];
#pragma unroll
  for (int cs = 0; cs < 8; ++cs)
    ws[cs] = *(const bf16x8*)(g_wsp + ((size_t)cs * 64 + l) * 8);

  const float bgv = bg[wid * 32 + lr];
  const float b0 = bsc[0], b1 = bsc[1], b2 = bsc[2], b3 = bsc[3], b4 = bsc[4];

  // pipelined staging payload
  float4 pay[16];
  float  bv[8];

  auto issue = [&](int tile) {
    const int p0 = tile * ROWS;
#pragma unroll
    for (int i = 0; i < 8; ++i) {
      int u = t + i * 256, row = u >> 5, slot = u & 31;
      const float* src = (slot < 16)
          ? lp + (size_t)(p0 + row) * H + slot * 8
          : gp + (size_t)(p0 + row) * H + (slot - 16) * 8;
      pay[2 * i]     = ((const float4*)src)[0];
      pay[2 * i + 1] = ((const float4*)src)[1];
    }
    if (t < 2 * ROWS) {
      int row = t >> 1, bh = t & 1, prow = p0 + row;
      int bi = sidx[(prow * 3 + 0) * sflag];
      int ii = sidx[(prow * 3 + 1) * sflag];
      int jj = sidx[(prow * 3 + 2) * sflag];
      int base = ((bi * 100 + ii) * 100 + jj) * NBINF;
#pragma unroll
      for (int j = 0; j < 8; ++j) {
        int e = bh * 8 + j;
        bv[j] = (e < NBINF) ? bin[base + e] : 0.f;
      }
    }
  };

  auto commit = [&](int buf) { // cvt + LDS write (compiler inserts vmcnt at first use)
    char* dst = sm + buf * ABUF;
#pragma unroll
    for (int i = 0; i < 8; ++i) {
      int u = t + i * 256, row = u >> 5, slot = u & 31;
      float4 a = pay[2 * i], b = pay[2 * i + 1];
      bf16x8 v;
      v[0] = (__bf16)a.x; v[1] = (__bf16)a.y; v[2] = (__bf16)a.z; v[3] = (__bf16)a.w;
      v[4] = (__bf16)b.x; v[5] = (__bf16)b.y; v[6] = (__bf16)b.z; v[7] = (__bf16)b.w;
      *(bf16x8*)(dst + row * ASTRIDE + slot * 16) = v;
    }
    if (t < 2 * ROWS) {
      int row = t >> 1, bh = t & 1;
      bf16x8 v;
#pragma unroll
      for (int j = 0; j < 8; ++j) v[j] = (__bf16)bv[j];
      *(bf16x8*)(dst + row * ASTRIDE + 512 + bh * 16) = v;
    }
  };

  // prologue: stage first tile
  const int tile0 = blockIdx.x;
  issue(tile0);
  commit(0);
  bar_lgkm();

  int cur = 0;
  for (int tile = tile0; tile < NT; tile += GRID) {
    const int nxt = tile + GRID;
    if (nxt < NT) issue(nxt); // fire-and-forget prefetch

    // ---- main GEMM from LDS[cur], weights in regs ----
    const char* A = sm + cur * ABUF;
    f32x16 acc[2] = {};
#pragma unroll
    for (int c = 0; c < NCHUNK; ++c) {
#pragma unroll
      for (int rt = 0; rt < 2; ++rt) {
        bf16x8 a = *(const bf16x8*)(A + (rt * 32 + lr) * ASTRIDE + c * 32 + lh * 16);
        acc[rt] = __builtin_amdgcn_mfma_f32_32x32x16_bf16(a, wreg[c], acc[rt], 0, 0, 0);
      }
    }
    bar_lgkm(); // BAR1: all A[cur] reads done (feat buffer overlays A[cur])

    // ---- bias+relu -> feat LDS (bf16 [row][h], stride 272B) ----
    {
      char* F = sm + cur * ABUF;
#pragma unroll
      for (int rt = 0; rt < 2; ++rt) {
#pragma unroll
        for (int rg = 0; rg < 16; ++rg) {
          int rowt = (rg & 3) + ((rg >> 2) << 3) + (lh << 2);
          float fv = fmaxf(acc[rt][rg] + bgv, 0.f);
          *(__bf16*)(F + (size_t)(rt * 32 + rowt) * FSTRIDE +
                     (size_t)(wid * 32 + lr) * 2) = (__bf16)fv;
        }
      }
    }
    bar_lgkm(); // BAR2: feats visible

    // ---- score GEMM (transposed): D[s][prow], waves 0,1 ----
    if (wid < 2) {
      const char* F = sm + cur * ABUF;
      f32x16 sacc = {};
#pragma unroll
      for (int cs = 0; cs < 8; ++cs) {
        bf16x8 fb = *(const bf16x8*)(F + (size_t)(wid * 32 + lr) * FSTRIDE +
                                     cs * 32 + lh * 16);
        sacc = __builtin_amdgcn_mfma_f32_32x32x16_bf16(ws[cs], fb, sacc, 0, 0, 0);
      }
      int prow = tile * ROWS + wid * 32 + lr;
      float* op = out + (size_t)prow * 5;
      if (lh == 0) { // rg 0..3 -> s=0..3
        op[0] = sacc[0] + b0; op[1] = sacc[1] + b1;
        op[2] = sacc[2] + b2; op[3] = sacc[3] + b3;
      } else {       // rg 0 -> s=4
        op[4] = sacc[0] + b4;
      }
    }

    if (nxt < NT) commit(cur ^ 1); // vmcnt lands here, then LDS writes
    bar_lgkm(); // BAR3: next tile's A visible
    cur ^= 1;
  }
}

extern "C" void kernel_launch(void* const* d_in, const int* in_sizes, int n_in,
                              void* d_out, int out_size, void* d_ws, size_t ws_size,
                              hipStream_t stream) {
  const float* lp  = (const float*)d_in[0];
  const float* gp  = (const float*)d_in[1];
  const float* bin = (const float*)d_in[2];
  const int*   si  = (const int*)d_in[3];
  const float* Wl  = (const float*)d_in[4];
  const float* Wg  = (const float*)d_in[5];
  const float* bg  = (const float*)d_in[6];
  const float* Wb  = (const float*)d_in[7];
  const float* Wsc = (const float*)d_in[8];
  const float* bsc = (const float*)d_in[9];
  float* out = (float*)d_out;

  hipLaunchKernelGGL(k_flag, dim3(1), dim3(64), 0, stream, si);
  hipLaunchKernelGGL(k_pack, dim3(136), dim3(256), 0, stream, Wl, Wg, Wb, Wsc);
  hipLaunchKernelGGL(k_main, dim3(GRID), dim3(256), 0, stream,
                     lp, gp, bin, si, bg, bsc, out);
}